// Round 1
// baseline (98.606 us; speedup 1.0000x reference)
//
#include <hip/hip_runtime.h>
#include <math.h>

namespace {

constexpr int kN = 128 * 128 * 128;   // grid points
constexpr int kC = 16;                // channels
constexpr int kB = 32;                // rays
constexpr float kCull = -21.0f;       // exp(-21) ~ 7.6e-10 -> negligible

__global__ void zero_kernel(float* __restrict__ out, int n) {
    int i = blockIdx.x * blockDim.x + threadIdx.x;
    if (i < n) out[i] = 0.0f;
}

__global__ __launch_bounds__(256)
void hpm_read_kernel(const float* __restrict__ memory,
                     const float* __restrict__ ray_o,
                     const float* __restrict__ ray_d,
                     float* __restrict__ out)
{
    __shared__ float4 sray[kB][2];     // [b][0]=origin, [b][1]=dir
    __shared__ float  acc[kB * kC];    // per-block partial output

    const int tid = threadIdx.x;
    if (tid < kB) {
        const float* o = ray_o + 3 * tid;
        const float* d = ray_d + 3 * tid;
        sray[tid][0] = make_float4(o[0], o[1], o[2], 0.0f);
        sray[tid][1] = make_float4(d[0], d[1], d[2], 0.0f);
    }
    for (int i = tid; i < kB * kC; i += blockDim.x) acc[i] = 0.0f;
    __syncthreads();

    const float4* __restrict__ mem4 = reinterpret_cast<const float4*>(memory);
    const int stride = gridDim.x * blockDim.x;

    for (int idx = blockIdx.x * blockDim.x + tid; idx < kN; idx += stride) {
        // grid point coordinates are implied by the linear index (ij meshgrid)
        const float pz = (float)(idx & 127);
        const float py = (float)((idx >> 7) & 127);
        const float px = (float)(idx >> 14);

        #pragma unroll 4
        for (int b = 0; b < kB; ++b) {
            const float4 o = sray[b][0];
            const float4 d = sray[b][1];
            const float dx = px - o.x, dy = py - o.y, dz = pz - o.z;
            const float nb2 = dx * dx + dy * dy + dz * dz;
            const float t   = dx * d.x + dy * d.y + dz * d.z;
            const float mt  = fmaxf(t, 0.0f);
            // cheap cull: r2c = nb2 - t^2 (cancellation error ~1e-2, fine for a
            // -21 threshold whose neighborhood contributes k < 1e-9)
            const float argc = 2.0f * fmaf(t, t, -nb2) - 0.5f * mt;
            if (argc > kCull) {
                // accurate r2 = |dx - t*d|^2 (no cancellation)
                const float ex = dx - t * d.x;
                const float ey = dy - t * d.y;
                const float ez = dz - t * d.z;
                const float r2 = ex * ex + ey * ey + ez * ez;
                const float k = __expf(fmaf(-2.0f, r2, -0.5f * mt));
                const float4 m0 = mem4[idx * 4 + 0];
                const float4 m1 = mem4[idx * 4 + 1];
                const float4 m2 = mem4[idx * 4 + 2];
                const float4 m3 = mem4[idx * 4 + 3];
                float* a = acc + b * kC;
                atomicAdd(a +  0, k * m0.x); atomicAdd(a +  1, k * m0.y);
                atomicAdd(a +  2, k * m0.z); atomicAdd(a +  3, k * m0.w);
                atomicAdd(a +  4, k * m1.x); atomicAdd(a +  5, k * m1.y);
                atomicAdd(a +  6, k * m1.z); atomicAdd(a +  7, k * m1.w);
                atomicAdd(a +  8, k * m2.x); atomicAdd(a +  9, k * m2.y);
                atomicAdd(a + 10, k * m2.z); atomicAdd(a + 11, k * m2.w);
                atomicAdd(a + 12, k * m3.x); atomicAdd(a + 13, k * m3.y);
                atomicAdd(a + 14, k * m3.z); atomicAdd(a + 15, k * m3.w);
            }
        }
    }
    __syncthreads();
    for (int i = tid; i < kB * kC; i += blockDim.x) {
        unsafeAtomicAdd(out + i, acc[i]);   // hardware global_atomic_add_f32
    }
}

} // namespace

extern "C" void kernel_launch(void* const* d_in, const int* in_sizes, int n_in,
                              void* d_out, int out_size, void* d_ws, size_t ws_size,
                              hipStream_t stream) {
    const float* memory = (const float*)d_in[0];
    // d_in[1] = grid : unused, coordinates are recomputed from the index
    const float* ray_o  = (const float*)d_in[2];
    const float* ray_d  = (const float*)d_in[3];
    float* out = (float*)d_out;

    zero_kernel<<<1, 512, 0, stream>>>(out, kB * kC);
    hpm_read_kernel<<<1024, 256, 0, stream>>>(memory, ray_o, ray_d, out);
}